// Round 1
// baseline (1409.601 us; speedup 1.0000x reference)
//
#include <hip/hip_runtime.h>
#include <stdint.h>

#define D_IN 1024
#define C1   1024   // H1*HID
#define C2   256    // H2*HID
#define NEG  0.2f

typedef unsigned int u32;
typedef uint16_t u16;
typedef __attribute__((ext_vector_type(8))) short bf16x8;
typedef __attribute__((ext_vector_type(4))) float f32x4;

__device__ __forceinline__ float bf2f(u32 lo16) { return __uint_as_float(lo16 << 16); }
__device__ __forceinline__ u16 f2bf(float f) {
  u32 u = __float_as_uint(f);
  u += 0x7fffu + ((u >> 16) & 1u);   // RNE
  return (u16)(u >> 16);
}
// monotone float<->uint mapping for atomicMax on floats
__device__ __forceinline__ u32 fmap(float f) {
  u32 u = __float_as_uint(f);
  return (u & 0x80000000u) ? ~u : (u | 0x80000000u);
}
__device__ __forceinline__ float funmap(u32 m) {
  u32 u = (m & 0x80000000u) ? (m ^ 0x80000000u) : ~m;
  return __uint_as_float(u);
}

__device__ __forceinline__ void gload16(const u16* g, u16* l) {
  __builtin_amdgcn_global_load_lds(
      (const __attribute__((address_space(1))) unsigned int*)g,
      (__attribute__((address_space(3))) unsigned int*)l,
      16, 0, 0);
}

// ---------------- cast x (f32) -> padded bf16 A [Mp][1024], zero pad rows ----
__global__ void cast_x_k(const float* __restrict__ x, u16* __restrict__ A,
                         int nrows, int Mp) {
  long long idx = (long long)blockIdx.x * blockDim.x + threadIdx.x;
  long long total = (long long)Mp * (D_IN / 8);
  if (idx >= total) return;
  long long base = idx * 8;
  int row = (int)(base >> 10);  // D_IN==1024
  u32 o0 = 0, o1 = 0, o2 = 0, o3 = 0;
  if (row < nrows) {
    const float4* px = (const float4*)(x + base);
    float4 v0 = px[0], v1 = px[1];
    o0 = (u32)f2bf(v0.x) | ((u32)f2bf(v0.y) << 16);
    o1 = (u32)f2bf(v0.z) | ((u32)f2bf(v0.w) << 16);
    o2 = (u32)f2bf(v1.x) | ((u32)f2bf(v1.y) << 16);
    o3 = (u32)f2bf(v1.z) | ((u32)f2bf(v1.w) << 16);
  }
  *(uint4*)(A + base) = make_uint4(o0, o1, o2, o3);
}

// ---------------- transpose+cast W [K][Nc] f32 -> Wt [Nc][K] bf16 ------------
__global__ void transpose_cast_k(const float* __restrict__ W, u16* __restrict__ Wt,
                                 int K, int Nc) {
  __shared__ float sh[32][33];
  int k0 = blockIdx.x * 32, n0 = blockIdx.y * 32;
  int tx = threadIdx.x, ty = threadIdx.y;  // block (32,8)
#pragma unroll
  for (int i = 0; i < 32; i += 8)
    sh[ty + i][tx] = W[(long long)(k0 + ty + i) * Nc + (n0 + tx)];
  __syncthreads();
#pragma unroll
  for (int i = 0; i < 32; i += 8)
    Wt[(long long)(n0 + ty + i) * K + (k0 + tx)] = f2bf(sh[tx][ty + i]);
}

// ---------------- bf16 MFMA GEMM: C[M][TN] = A[M][K] * Bt[TN][K]^T + bias ----
// 128x128 tile, BK=32, 4 waves each computing a 64x64 quadrant via 4x4 16x16 frags.
// LDS XOR-swizzle (16B granularity) applied by pre-swizzling the global source
// (rule #21): physical (row,kg) holds logical kg^(row&3).
template <int TN>
__global__ __launch_bounds__(256) void gemm_bt_k(
    const u16* __restrict__ A, const u16* __restrict__ Bt,
    const float* __restrict__ bias, u16* __restrict__ C, int K) {
  __shared__ u16 As[128 * 32];
  __shared__ u16 Bs[128 * 32];
  const int tid = threadIdx.x;
  const int lane = tid & 63;
  const int wave = tid >> 6;
  const int m0 = blockIdx.x * 128;
  const int n0 = blockIdx.y * 128;
  const int wr = wave >> 1, wc = wave & 1;

  f32x4 acc[4][4] = {};

  // staging: thread tid handles LDS bytes tid*16 of each 4KB half-tile
  const int srow = tid >> 2;                      // 0..63
  const int kgp = tid & 3;                        // physical k-group
  const int scol = (kgp ^ (srow & 3)) * 8;        // swizzled source col
  const u16* gA0 = A + (long long)(m0 + srow) * K + scol;
  const u16* gA1 = A + (long long)(m0 + 64 + srow) * K + scol;
  const u16* gB0 = Bt + (long long)(n0 + srow) * K + scol;
  const u16* gB1 = Bt + (long long)(n0 + 64 + srow) * K + scol;
  u16* lA = As + wave * 512;
  u16* lB = Bs + wave * 512;

  for (int k0 = 0; k0 < K; k0 += 32) {
    gload16(gA0 + k0, lA);
    gload16(gA1 + k0, lA + 2048);
    gload16(gB0 + k0, lB);
    gload16(gB1 + k0, lB + 2048);
    asm volatile("s_waitcnt vmcnt(0)" ::: "memory");
    __syncthreads();

    bf16x8 av[4], bv[4];
#pragma unroll
    for (int m = 0; m < 4; m++) {
      int row = wr * 64 + m * 16 + (lane & 15);
      int kg = (lane >> 4) ^ (row & 3);
      av[m] = *(const bf16x8*)(As + row * 32 + kg * 8);
    }
#pragma unroll
    for (int n = 0; n < 4; n++) {
      int row = wc * 64 + n * 16 + (lane & 15);
      int kg = (lane >> 4) ^ (row & 3);
      bv[n] = *(const bf16x8*)(Bs + row * 32 + kg * 8);
    }
#pragma unroll
    for (int m = 0; m < 4; m++)
#pragma unroll
      for (int n = 0; n < 4; n++)
        acc[m][n] = __builtin_amdgcn_mfma_f32_16x16x32_bf16(av[m], bv[n], acc[m][n], 0, 0, 0);
    __syncthreads();
  }

  // epilogue: D mapping col=lane&15, row=(lane>>4)*4+j
#pragma unroll
  for (int m = 0; m < 4; m++) {
    int r0 = m0 + wr * 64 + m * 16 + ((lane >> 4) << 2);
#pragma unroll
    for (int n = 0; n < 4; n++) {
      int c = n0 + wc * 64 + n * 16 + (lane & 15);
      float b = bias[c];
#pragma unroll
      for (int j = 0; j < 4; j++)
        C[(long long)(r0 + j) * TN + c] = f2bf(acc[m][n][j] + b);
    }
  }
}

// ---------------- per-edge attention logits, layer 1 (H=4, C=256) ------------
__global__ void alpha1_k(const u16* __restrict__ XL, const u16* __restrict__ XR,
                         const int* __restrict__ ei, const float* __restrict__ att,
                         float* __restrict__ alpha, int E0, int E) {
  int e = blockIdx.x * 4 + (threadIdx.x >> 6);
  if (e >= E) return;
  int lane = threadIdx.x & 63;
  int src, dst;
  if (e < E0) { src = ei[e]; dst = ei[E0 + e]; } else { src = dst = e - E0; }
  const u16* xl = XL + (long long)src * C1 + lane * 16;
  const u16* xr = XR + (long long)dst * C1 + lane * 16;
  uint4 l0 = *(const uint4*)xl, l1 = *(const uint4*)(xl + 8);
  uint4 r0 = *(const uint4*)xr, r1 = *(const uint4*)(xr + 8);
  u32 L[8] = {l0.x, l0.y, l0.z, l0.w, l1.x, l1.y, l1.z, l1.w};
  u32 R[8] = {r0.x, r0.y, r0.z, r0.w, r1.x, r1.y, r1.z, r1.w};
  const float* at = att + lane * 16;  // att flat [4*256]; head = lane/16
  float s = 0.f;
#pragma unroll
  for (int q = 0; q < 8; q++) {
    float ma = bf2f(L[q] & 0xffffu) + bf2f(R[q] & 0xffffu);
    float mb = bf2f(L[q] >> 16) + bf2f(R[q] >> 16);
    ma = ma > 0.f ? ma : NEG * ma;
    mb = mb > 0.f ? mb : NEG * mb;
    s += at[2 * q] * ma + at[2 * q + 1] * mb;
  }
#pragma unroll
  for (int off = 1; off < 16; off <<= 1) s += __shfl_xor(s, off);
  if ((lane & 15) == 0) alpha[(long long)e * 4 + (lane >> 4)] = s;
}

// ---------------- per-edge attention logits, layer 2 (H=1, C=256) ------------
__global__ void alpha2_k(const u16* __restrict__ XL, const u16* __restrict__ XR,
                         const int* __restrict__ ei, const float* __restrict__ att,
                         float* __restrict__ alpha, int E0, int E) {
  int e = blockIdx.x * 4 + (threadIdx.x >> 6);
  if (e >= E) return;
  int lane = threadIdx.x & 63;
  int src, dst;
  if (e < E0) { src = ei[e]; dst = ei[E0 + e]; } else { src = dst = e - E0; }
  uint2 l = *(const uint2*)(XL + (long long)src * C2 + lane * 4);
  uint2 r = *(const uint2*)(XR + (long long)dst * C2 + lane * 4);
  u32 L[2] = {l.x, l.y}, R[2] = {r.x, r.y};
  const float* at = att + lane * 4;
  float s = 0.f;
#pragma unroll
  for (int q = 0; q < 2; q++) {
    float ma = bf2f(L[q] & 0xffffu) + bf2f(R[q] & 0xffffu);
    float mb = bf2f(L[q] >> 16) + bf2f(R[q] >> 16);
    ma = ma > 0.f ? ma : NEG * ma;
    mb = mb > 0.f ? mb : NEG * mb;
    s += at[2 * q] * ma + at[2 * q + 1] * mb;
  }
#pragma unroll
  for (int off = 1; off < 64; off <<= 1) s += __shfl_xor(s, off);
  if (lane == 0) alpha[e] = s;
}

// ---------------- segment softmax stats ------------------------------------
template <int H>
__global__ void seg_max_k(const float* __restrict__ alpha, const int* __restrict__ ei,
                          u32* __restrict__ amax_u, int E0, int E) {
  int total = E * H;
  for (int idx = blockIdx.x * blockDim.x + threadIdx.x; idx < total;
       idx += gridDim.x * blockDim.x) {
    int e = idx / H, h = idx - e * H;
    int dst = (e < E0) ? ei[E0 + e] : e - E0;
    atomicMax(&amax_u[dst * H + h], fmap(alpha[idx]));
  }
}

template <int H>
__global__ void seg_expsum_k(float* __restrict__ alpha, const int* __restrict__ ei,
                             const u32* __restrict__ amax_u, float* __restrict__ denom,
                             int E0, int E) {
  int total = E * H;
  for (int idx = blockIdx.x * blockDim.x + threadIdx.x; idx < total;
       idx += gridDim.x * blockDim.x) {
    int e = idx / H, h = idx - e * H;
    int dst = (e < E0) ? ei[E0 + e] : e - E0;
    float ex = __expf(alpha[idx] - funmap(amax_u[dst * H + h]));
    alpha[idx] = ex;
    atomicAdd(&denom[dst * H + h], ex);
  }
}

// ---------------- CSR build (by dst) ----------------------------------------
__global__ void count_k(const int* __restrict__ ei, int* __restrict__ counts,
                        int E0, int E) {
  for (int e = blockIdx.x * blockDim.x + threadIdx.x; e < E;
       e += gridDim.x * blockDim.x) {
    int dst = (e < E0) ? ei[E0 + e] : e - E0;
    atomicAdd(&counts[dst], 1);
  }
}

__global__ void scan_k(const int* __restrict__ counts, int* __restrict__ indptr, int n) {
  __shared__ int sh[256];
  __shared__ int carry_s;
  if (threadIdx.x == 0) carry_s = 0;
  __syncthreads();
  for (int base = 0; base < n; base += 256) {
    int i = base + threadIdx.x;
    int v = (i < n) ? counts[i] : 0;
    sh[threadIdx.x] = v;
    __syncthreads();
    int sum = v;
    for (int off = 1; off < 256; off <<= 1) {
      int t = (threadIdx.x >= off) ? sh[threadIdx.x - off] : 0;
      __syncthreads();
      sum += t;
      sh[threadIdx.x] = sum;
      __syncthreads();
    }
    int carry = carry_s;
    if (i < n) indptr[i] = carry + sum - v;
    __syncthreads();
    if (threadIdx.x == 255) carry_s = carry + sh[255];
    __syncthreads();
  }
  if (threadIdx.x == 0) indptr[n] = carry_s;
}

__global__ void scatter_k(const int* __restrict__ ei, const int* __restrict__ indptr,
                          int* __restrict__ cursor, int* __restrict__ eidx,
                          int E0, int E) {
  for (int e = blockIdx.x * blockDim.x + threadIdx.x; e < E;
       e += gridDim.x * blockDim.x) {
    int dst = (e < E0) ? ei[E0 + e] : e - E0;
    int pos = atomicAdd(&cursor[dst], 1);
    eidx[indptr[dst] + pos] = e;
  }
}

// ---------------- aggregation layer 1: one block per dst --------------------
// out = relu(sum_e a*xl[src] + bias1) -> bf16 X2 (layer-2 GEMM input)
__global__ __launch_bounds__(256) void agg1_k(
    const u16* __restrict__ XL, const float* __restrict__ alpha,
    const float* __restrict__ denom, const int* __restrict__ indptr,
    const int* __restrict__ eidx, const int* __restrict__ ei,
    const float* __restrict__ bias, u16* __restrict__ X2, int E0) {
  int d = blockIdx.x;
  int tid = threadIdx.x;
  int c0 = tid * 4;
  int h = tid >> 6;  // c0/256
  float inv = 1.0f / (denom[d * 4 + h] + 1e-16f);
  float a0 = 0.f, a1 = 0.f, a2 = 0.f, a3 = 0.f;
  int pend = indptr[d + 1];
  for (int p = indptr[d]; p < pend; ++p) {
    int e = eidx[p];
    int src = (e < E0) ? ei[e] : e - E0;
    float w = alpha[(long long)e * 4 + h] * inv;
    ushort4 v = *(const ushort4*)(XL + (long long)src * C1 + c0);
    a0 += w * bf2f(v.x); a1 += w * bf2f(v.y);
    a2 += w * bf2f(v.z); a3 += w * bf2f(v.w);
  }
  float4 b = *(const float4*)(bias + c0);
  ushort4 o;
  o.x = f2bf(fmaxf(a0 + b.x, 0.f));
  o.y = f2bf(fmaxf(a1 + b.y, 0.f));
  o.z = f2bf(fmaxf(a2 + b.z, 0.f));
  o.w = f2bf(fmaxf(a3 + b.w, 0.f));
  *(ushort4*)(X2 + (long long)d * C1 + c0) = o;
}

// ---------------- aggregation layer 2: one wave per dst, f32 out ------------
__global__ __launch_bounds__(64) void agg2_k(
    const u16* __restrict__ XL, const float* __restrict__ alpha,
    const float* __restrict__ denom, const int* __restrict__ indptr,
    const int* __restrict__ eidx, const int* __restrict__ ei,
    const float* __restrict__ bias, float* __restrict__ out, int E0) {
  int d = blockIdx.x;
  int tid = threadIdx.x;
  int c0 = tid * 4;
  float inv = 1.0f / (denom[d] + 1e-16f);
  float a0 = 0.f, a1 = 0.f, a2 = 0.f, a3 = 0.f;
  int pend = indptr[d + 1];
  for (int p = indptr[d]; p < pend; ++p) {
    int e = eidx[p];
    int src = (e < E0) ? ei[e] : e - E0;
    float w = alpha[e] * inv;
    ushort4 v = *(const ushort4*)(XL + (long long)src * C2 + c0);
    a0 += w * bf2f(v.x); a1 += w * bf2f(v.y);
    a2 += w * bf2f(v.z); a3 += w * bf2f(v.w);
  }
  float4 b = *(const float4*)(bias + c0);
  float4 o;
  o.x = fmaxf(a0 + b.x, 0.f);
  o.y = fmaxf(a1 + b.y, 0.f);
  o.z = fmaxf(a2 + b.z, 0.f);
  o.w = fmaxf(a3 + b.w, 0.f);
  *(float4*)(out + (long long)d * C2 + c0) = o;
}

// =============================================================================
extern "C" void kernel_launch(void* const* d_in, const int* in_sizes, int n_in,
                              void* d_out, int out_size, void* d_ws, size_t ws_size,
                              hipStream_t stream) {
  const float* x     = (const float*)d_in[0];
  const int*   ei    = (const int*)d_in[1];
  const float* W1l   = (const float*)d_in[2];
  const float* b1l   = (const float*)d_in[3];
  const float* W1r   = (const float*)d_in[4];
  const float* b1r   = (const float*)d_in[5];
  const float* att1  = (const float*)d_in[6];
  const float* bias1 = (const float*)d_in[7];
  const float* W2l   = (const float*)d_in[8];
  const float* b2l   = (const float*)d_in[9];
  const float* W2r   = (const float*)d_in[10];
  const float* b2r   = (const float*)d_in[11];
  const float* att2  = (const float*)d_in[12];
  const float* bias2 = (const float*)d_in[13];

  const int N  = in_sizes[0] / D_IN;  // 50000
  const int E0 = in_sizes[1] / 2;     // 400000
  const int E  = E0 + N;              // 450000 (with self-loops)
  const int Mp = (N + 127) & ~127;    // 50048

  char* p = (char*)d_ws;
  auto alloc = [&](size_t bytes) -> char* {
    char* r = p;
    p += (bytes + 255) & ~(size_t)255;
    return r;
  };
  u16* A_bf  = (u16*)alloc((size_t)Mp * D_IN * 2);  // x bf16, later x2 bf16
  u16* XL1   = (u16*)alloc((size_t)Mp * C1 * 2);    // later XL2
  u16* XR1   = (u16*)alloc((size_t)Mp * C1 * 2);    // later XR2
  u16* W1lt  = (u16*)alloc((size_t)C1 * D_IN * 2);
  u16* W1rt  = (u16*)alloc((size_t)C1 * D_IN * 2);
  u16* W2lt  = (u16*)alloc((size_t)C2 * C1 * 2);
  u16* W2rt  = (u16*)alloc((size_t)C2 * C1 * 2);
  float* alpha = (float*)alloc((size_t)E * 4 * 4);
  u32* amax    = (u32*)alloc((size_t)N * 4 * 4);
  float* denom = (float*)alloc((size_t)N * 4 * 4);
  int* counts  = (int*)alloc((size_t)N * 4);
  int* cursor  = (int*)alloc((size_t)N * 4);
  int* indptr  = (int*)alloc((size_t)(N + 1) * 4);
  int* eidx    = (int*)alloc((size_t)E * 4);
  u16* XL2 = XL1;  // alias: XL1 dead before layer-2 GEMMs
  u16* XR2 = XR1;

  size_t need = (size_t)(p - (char*)d_ws);
  if (ws_size < need) {
    // distinctive failure sentinel (NaN in d_out[0])
    hipMemsetAsync(d_out, 0xFF, 4, stream);
    return;
  }

  // ---- init ----
  hipMemsetAsync(counts, 0, (size_t)N * 4, stream);
  hipMemsetAsync(cursor, 0, (size_t)N * 4, stream);
  hipMemsetAsync(amax, 0, (size_t)N * 16, stream);
  hipMemsetAsync(denom, 0, (size_t)N * 16, stream);

  // ---- casts / transposes ----
  {
    long long tot = (long long)Mp * (D_IN / 8);
    int blocks = (int)((tot + 255) / 256);
    cast_x_k<<<blocks, 256, 0, stream>>>(x, A_bf, N, Mp);
  }
  dim3 tb(32, 8);
  transpose_cast_k<<<dim3(D_IN / 32, C1 / 32), tb, 0, stream>>>(W1l, W1lt, D_IN, C1);
  transpose_cast_k<<<dim3(D_IN / 32, C1 / 32), tb, 0, stream>>>(W1r, W1rt, D_IN, C1);
  transpose_cast_k<<<dim3(C1 / 32, C2 / 32), tb, 0, stream>>>(W2l, W2lt, C1, C2);
  transpose_cast_k<<<dim3(C1 / 32, C2 / 32), tb, 0, stream>>>(W2r, W2rt, C1, C2);

  // ---- CSR by dst (shared by both layers) ----
  count_k<<<1024, 256, 0, stream>>>(ei, counts, E0, E);
  scan_k<<<1, 256, 0, stream>>>(counts, indptr, N);
  scatter_k<<<1024, 256, 0, stream>>>(ei, indptr, cursor, eidx, E0, E);

  // ---- layer 1 ----
  gemm_bt_k<C1><<<dim3(Mp / 128, C1 / 128), 256, 0, stream>>>(A_bf, W1lt, b1l, XL1, D_IN);
  gemm_bt_k<C1><<<dim3(Mp / 128, C1 / 128), 256, 0, stream>>>(A_bf, W1rt, b1r, XR1, D_IN);
  alpha1_k<<<(E + 3) / 4, 256, 0, stream>>>(XL1, XR1, ei, att1, alpha, E0, E);
  seg_max_k<4><<<1024, 256, 0, stream>>>(alpha, ei, amax, E0, E);
  seg_expsum_k<4><<<1024, 256, 0, stream>>>(alpha, ei, amax, denom, E0, E);
  agg1_k<<<N, 256, 0, stream>>>(XL1, alpha, denom, indptr, eidx, ei, bias1, A_bf, E0);

  // ---- layer 2 ----
  gemm_bt_k<C2><<<dim3(Mp / 128, C2 / 128), 256, 0, stream>>>(A_bf, W2lt, b2l, XL2, C1);
  gemm_bt_k<C2><<<dim3(Mp / 128, C2 / 128), 256, 0, stream>>>(A_bf, W2rt, b2r, XR2, C1);
  hipMemsetAsync(amax, 0, (size_t)N * 16, stream);
  hipMemsetAsync(denom, 0, (size_t)N * 16, stream);
  alpha2_k<<<(E + 3) / 4, 256, 0, stream>>>(XL2, XR2, ei, att2, alpha, E0, E);
  seg_max_k<1><<<1024, 256, 0, stream>>>(alpha, ei, amax, E0, E);
  seg_expsum_k<1><<<1024, 256, 0, stream>>>(alpha, ei, amax, denom, E0, E);
  agg2_k<<<N, 64, 0, stream>>>(XL2, alpha, denom, indptr, eidx, ei, bias2,
                               (float*)d_out, E0);
}

// Round 2
// 935.349 us; speedup vs baseline: 1.5070x; 1.5070x over previous
//
#include <hip/hip_runtime.h>
#include <stdint.h>

#define D_IN 1024
#define C1   1024   // H1*HID
#define C2   256    // H2*HID
#define NEG  0.2f

typedef unsigned int u32;
typedef uint16_t u16;
typedef __attribute__((ext_vector_type(8))) short bf16x8;
typedef __attribute__((ext_vector_type(4))) float f32x4;

__device__ __forceinline__ float bf2f(u32 lo16) { return __uint_as_float(lo16 << 16); }
__device__ __forceinline__ u16 f2bf(float f) {
  u32 u = __float_as_uint(f);
  u += 0x7fffu + ((u >> 16) & 1u);   // RNE
  return (u16)(u >> 16);
}

__device__ __forceinline__ void gload16(const u16* g, u16* l) {
  __builtin_amdgcn_global_load_lds(
      (const __attribute__((address_space(1))) unsigned int*)g,
      (__attribute__((address_space(3))) unsigned int*)l,
      16, 0, 0);
}

// ---------------- cast x (f32) -> padded bf16 A [Mp][1024], zero pad rows ----
__global__ void cast_x_k(const float* __restrict__ x, u16* __restrict__ A,
                         int nrows, int Mp) {
  long long idx = (long long)blockIdx.x * blockDim.x + threadIdx.x;
  long long total = (long long)Mp * (D_IN / 8);
  if (idx >= total) return;
  long long base = idx * 8;
  int row = (int)(base >> 10);  // D_IN==1024
  u32 o0 = 0, o1 = 0, o2 = 0, o3 = 0;
  if (row < nrows) {
    const float4* px = (const float4*)(x + base);
    float4 v0 = px[0], v1 = px[1];
    o0 = (u32)f2bf(v0.x) | ((u32)f2bf(v0.y) << 16);
    o1 = (u32)f2bf(v0.z) | ((u32)f2bf(v0.w) << 16);
    o2 = (u32)f2bf(v1.x) | ((u32)f2bf(v1.y) << 16);
    o3 = (u32)f2bf(v1.z) | ((u32)f2bf(v1.w) << 16);
  }
  *(uint4*)(A + base) = make_uint4(o0, o1, o2, o3);
}

// ---------------- transpose+cast W [K][Nc] f32 -> Wt [Nc][K] bf16 ------------
__global__ void transpose_cast_k(const float* __restrict__ W, u16* __restrict__ Wt,
                                 int K, int Nc) {
  __shared__ float sh[32][33];
  int k0 = blockIdx.x * 32, n0 = blockIdx.y * 32;
  int tx = threadIdx.x, ty = threadIdx.y;  // block (32,8)
#pragma unroll
  for (int i = 0; i < 32; i += 8)
    sh[ty + i][tx] = W[(long long)(k0 + ty + i) * Nc + (n0 + tx)];
  __syncthreads();
#pragma unroll
  for (int i = 0; i < 32; i += 8)
    Wt[(long long)(n0 + ty + i) * K + (k0 + tx)] = f2bf(sh[tx][ty + i]);
}

// ---------------- concat two bias vectors -----------------------------------
__global__ void concat_bias_k(const float* __restrict__ a, const float* __restrict__ b,
                              float* __restrict__ o, int na, int nb) {
  int i = blockIdx.x * 256 + threadIdx.x;
  if (i < na) o[i] = a[i];
  else if (i < na + nb) o[i] = b[i - na];
}

// ---------------- bf16 MFMA GEMM: C[M][TN] = A[M][K] * Bt[TN][K]^T + bias ----
// 128x128 tile, BK=32, 4 waves x (4x4 16x16x32 frags). XOR-swizzled LDS via
// pre-swizzled global source (both-sides rule #21). Bijective XCD swizzle (T1).
template <int TN>
__global__ __launch_bounds__(256) void gemm_bt_k(
    const u16* __restrict__ A, const u16* __restrict__ Bt,
    const float* __restrict__ bias, u16* __restrict__ C, int K) {
  __shared__ u16 As[128 * 32];
  __shared__ u16 Bs[128 * 32];
  const int nx = gridDim.x, ny = gridDim.y;
  const int nwg = nx * ny;
  int id = blockIdx.y * nx + blockIdx.x;
  int q = nwg >> 3, r = nwg & 7;
  int xcd = id & 7, loc = id >> 3;
  int sid = (xcd < r ? xcd * (q + 1) : r * (q + 1) + (xcd - r) * q) + loc;
  const int m0 = (sid % nx) * 128;
  const int n0 = (sid / nx) * 128;

  const int tid = threadIdx.x;
  const int lane = tid & 63;
  const int wave = tid >> 6;
  const int wr = wave >> 1, wc = wave & 1;

  f32x4 acc[4][4] = {};

  const int srow = tid >> 2;                      // 0..63
  const int kgp = tid & 3;                        // physical k-group
  const int scol = (kgp ^ (srow & 3)) * 8;        // swizzled source col
  const u16* gA0 = A + (long long)(m0 + srow) * K + scol;
  const u16* gA1 = A + (long long)(m0 + 64 + srow) * K + scol;
  const u16* gB0 = Bt + (long long)(n0 + srow) * K + scol;
  const u16* gB1 = Bt + (long long)(n0 + 64 + srow) * K + scol;
  u16* lA = As + wave * 512;
  u16* lB = Bs + wave * 512;

  for (int k0 = 0; k0 < K; k0 += 32) {
    gload16(gA0 + k0, lA);
    gload16(gA1 + k0, lA + 2048);
    gload16(gB0 + k0, lB);
    gload16(gB1 + k0, lB + 2048);
    asm volatile("s_waitcnt vmcnt(0)" ::: "memory");
    __syncthreads();

    bf16x8 av[4], bv[4];
#pragma unroll
    for (int m = 0; m < 4; m++) {
      int row = wr * 64 + m * 16 + (lane & 15);
      int kg = (lane >> 4) ^ (row & 3);
      av[m] = *(const bf16x8*)(As + row * 32 + kg * 8);
    }
#pragma unroll
    for (int n = 0; n < 4; n++) {
      int row = wc * 64 + n * 16 + (lane & 15);
      int kg = (lane >> 4) ^ (row & 3);
      bv[n] = *(const bf16x8*)(Bs + row * 32 + kg * 8);
    }
#pragma unroll
    for (int m = 0; m < 4; m++)
#pragma unroll
      for (int n = 0; n < 4; n++)
        acc[m][n] = __builtin_amdgcn_mfma_f32_16x16x32_bf16(av[m], bv[n], acc[m][n], 0, 0, 0);
    __syncthreads();
  }

#pragma unroll
  for (int m = 0; m < 4; m++) {
    int r0 = m0 + wr * 64 + m * 16 + ((lane >> 4) << 2);
#pragma unroll
    for (int n = 0; n < 4; n++) {
      int c = n0 + wc * 64 + n * 16 + (lane & 15);
      float b = bias[c];
#pragma unroll
      for (int j = 0; j < 4; j++)
        C[(long long)(r0 + j) * TN + c] = f2bf(acc[m][n][j] + b);
    }
  }
}

// ---------------- CSR build (by dst) ----------------------------------------
__global__ void count_k(const int* __restrict__ ei, int* __restrict__ counts,
                        int E0, int E) {
  for (int e = blockIdx.x * blockDim.x + threadIdx.x; e < E;
       e += gridDim.x * blockDim.x) {
    int dst = (e < E0) ? ei[E0 + e] : e - E0;
    atomicAdd(&counts[dst], 1);
  }
}

__global__ void scan_k(const int* __restrict__ counts, int* __restrict__ indptr, int n) {
  __shared__ int sh[256];
  __shared__ int carry_s;
  if (threadIdx.x == 0) carry_s = 0;
  __syncthreads();
  for (int base = 0; base < n; base += 256) {
    int i = base + threadIdx.x;
    int v = (i < n) ? counts[i] : 0;
    sh[threadIdx.x] = v;
    __syncthreads();
    int sum = v;
    for (int off = 1; off < 256; off <<= 1) {
      int t = (threadIdx.x >= off) ? sh[threadIdx.x - off] : 0;
      __syncthreads();
      sum += t;
      sh[threadIdx.x] = sum;
      __syncthreads();
    }
    int carry = carry_s;
    if (i < n) indptr[i] = carry + sum - v;
    __syncthreads();
    if (threadIdx.x == 255) carry_s = carry + sh[255];
    __syncthreads();
  }
  if (threadIdx.x == 0) indptr[n] = carry_s;
}

// store SRC id (not edge id) in CSR order
__global__ void scatter_k(const int* __restrict__ ei, const int* __restrict__ indptr,
                          int* __restrict__ cursor, int* __restrict__ esrc,
                          int E0, int E) {
  for (int e = blockIdx.x * blockDim.x + threadIdx.x; e < E;
       e += gridDim.x * blockDim.x) {
    int dst, src;
    if (e < E0) { src = ei[e]; dst = ei[E0 + e]; } else { src = dst = e - E0; }
    int pos = atomicAdd(&cursor[dst], 1);
    esrc[indptr[dst] + pos] = src;
  }
}

// ---------------- fused edge layer 1 (H=4): alpha+softmax+agg, online --------
// Block of 256 = 4 waves; wave h handles head h (256 ch, 4/lane).
// XLR: [Mp][2048] bf16 (cols 0..1023 = xl, 1024..2047 = xr).
// Out: X2 [Mp][1024] bf16 = relu(agg + bias); pad rows zeroed.
__global__ __launch_bounds__(256) void fused_edge1_k(
    const u16* __restrict__ XLR, const int* __restrict__ indptr,
    const int* __restrict__ esrc, const float* __restrict__ att,
    const float* __restrict__ bias, u16* __restrict__ X2, int N) {
  int d = blockIdx.x;
  int tid = threadIdx.x;
  int c0 = tid * 4;  // channel in [0,1024); head = tid>>6
  if (d >= N) {
    *(ushort4*)(X2 + (long long)d * C1 + c0) = make_ushort4(0, 0, 0, 0);
    return;
  }
  ushort4 xr4 = *(const ushort4*)(XLR + (long long)d * 2048 + 1024 + c0);
  float xr0 = bf2f(xr4.x), xr1 = bf2f(xr4.y), xr2 = bf2f(xr4.z), xr3 = bf2f(xr4.w);
  float4 at = *(const float4*)(att + c0);

  float m = -INFINITY, l = 0.f;
  float a0 = 0.f, a1 = 0.f, a2 = 0.f, a3 = 0.f;
  int p = indptr[d], pend = indptr[d + 1];
  int src = esrc[p];
  ushort4 xl4 = *(const ushort4*)(XLR + (long long)src * 2048 + c0);
  while (p < pend) {
    ushort4 cur = xl4;
    int pn = p + 1;
    if (pn < pend) {
      int sn = esrc[pn];
      xl4 = *(const ushort4*)(XLR + (long long)sn * 2048 + c0);
    }
    float x0 = bf2f(cur.x), x1 = bf2f(cur.y), x2 = bf2f(cur.z), x3 = bf2f(cur.w);
    float m0 = x0 + xr0, m1 = x1 + xr1, m2 = x2 + xr2, m3 = x3 + xr3;
    float e0 = m0 > 0.f ? m0 : NEG * m0;
    float e1 = m1 > 0.f ? m1 : NEG * m1;
    float e2 = m2 > 0.f ? m2 : NEG * m2;
    float e3 = m3 > 0.f ? m3 : NEG * m3;
    float s = at.x * e0 + at.y * e1 + at.z * e2 + at.w * e3;
#pragma unroll
    for (int off = 1; off < 64; off <<= 1) s += __shfl_xor(s, off);
    float mnew = fmaxf(m, s);
    float scale = __expf(m - mnew);  // first iter: exp(-inf)=0
    float w = __expf(s - mnew);
    l = l * scale + w;
    a0 = a0 * scale + w * x0;
    a1 = a1 * scale + w * x1;
    a2 = a2 * scale + w * x2;
    a3 = a3 * scale + w * x3;
    m = mnew;
    p = pn;
  }
  float inv = 1.f / (l + 1e-16f);
  float4 b = *(const float4*)(bias + c0);
  ushort4 o;
  o.x = f2bf(fmaxf(a0 * inv + b.x, 0.f));
  o.y = f2bf(fmaxf(a1 * inv + b.y, 0.f));
  o.z = f2bf(fmaxf(a2 * inv + b.z, 0.f));
  o.w = f2bf(fmaxf(a3 * inv + b.w, 0.f));
  *(ushort4*)(X2 + (long long)d * C1 + c0) = o;
}

// ---------------- fused edge layer 2 (H=1): one wave per dst, f32 out --------
// XLR: [Mp][512] bf16 (cols 0..255 = xl, 256..511 = xr).
__global__ __launch_bounds__(256) void fused_edge2_k(
    const u16* __restrict__ XLR, const int* __restrict__ indptr,
    const int* __restrict__ esrc, const float* __restrict__ att,
    const float* __restrict__ bias, float* __restrict__ out, int N) {
  int d = blockIdx.x * 4 + (threadIdx.x >> 6);
  if (d >= N) return;
  int lane = threadIdx.x & 63;
  int c0 = lane * 4;
  ushort4 xr4 = *(const ushort4*)(XLR + (long long)d * 512 + 256 + c0);
  float xr0 = bf2f(xr4.x), xr1 = bf2f(xr4.y), xr2 = bf2f(xr4.z), xr3 = bf2f(xr4.w);
  float4 at = *(const float4*)(att + c0);

  float m = -INFINITY, l = 0.f;
  float a0 = 0.f, a1 = 0.f, a2 = 0.f, a3 = 0.f;
  int p = indptr[d], pend = indptr[d + 1];
  int src = esrc[p];
  ushort4 xl4 = *(const ushort4*)(XLR + (long long)src * 512 + c0);
  while (p < pend) {
    ushort4 cur = xl4;
    int pn = p + 1;
    if (pn < pend) {
      int sn = esrc[pn];
      xl4 = *(const ushort4*)(XLR + (long long)sn * 512 + c0);
    }
    float x0 = bf2f(cur.x), x1 = bf2f(cur.y), x2 = bf2f(cur.z), x3 = bf2f(cur.w);
    float m0 = x0 + xr0, m1 = x1 + xr1, m2 = x2 + xr2, m3 = x3 + xr3;
    float e0 = m0 > 0.f ? m0 : NEG * m0;
    float e1 = m1 > 0.f ? m1 : NEG * m1;
    float e2 = m2 > 0.f ? m2 : NEG * m2;
    float e3 = m3 > 0.f ? m3 : NEG * m3;
    float s = at.x * e0 + at.y * e1 + at.z * e2 + at.w * e3;
#pragma unroll
    for (int off = 1; off < 64; off <<= 1) s += __shfl_xor(s, off);
    float mnew = fmaxf(m, s);
    float scale = __expf(m - mnew);
    float w = __expf(s - mnew);
    l = l * scale + w;
    a0 = a0 * scale + w * x0;
    a1 = a1 * scale + w * x1;
    a2 = a2 * scale + w * x2;
    a3 = a3 * scale + w * x3;
    m = mnew;
    p = pn;
  }
  float inv = 1.f / (l + 1e-16f);
  float4 b = *(const float4*)(bias + c0);
  float4 o;
  o.x = fmaxf(a0 * inv + b.x, 0.f);
  o.y = fmaxf(a1 * inv + b.y, 0.f);
  o.z = fmaxf(a2 * inv + b.z, 0.f);
  o.w = fmaxf(a3 * inv + b.w, 0.f);
  *(float4*)(out + (long long)d * C2 + c0) = o;
}

// =============================================================================
extern "C" void kernel_launch(void* const* d_in, const int* in_sizes, int n_in,
                              void* d_out, int out_size, void* d_ws, size_t ws_size,
                              hipStream_t stream) {
  const float* x     = (const float*)d_in[0];
  const int*   ei    = (const int*)d_in[1];
  const float* W1l   = (const float*)d_in[2];
  const float* b1l   = (const float*)d_in[3];
  const float* W1r   = (const float*)d_in[4];
  const float* b1r   = (const float*)d_in[5];
  const float* att1  = (const float*)d_in[6];
  const float* bias1 = (const float*)d_in[7];
  const float* W2l   = (const float*)d_in[8];
  const float* b2l   = (const float*)d_in[9];
  const float* W2r   = (const float*)d_in[10];
  const float* b2r   = (const float*)d_in[11];
  const float* att2  = (const float*)d_in[12];
  const float* bias2 = (const float*)d_in[13];

  const int N  = in_sizes[0] / D_IN;  // 50000
  const int E0 = in_sizes[1] / 2;     // 400000
  const int E  = E0 + N;              // with self-loops
  const int Mp = (N + 127) & ~127;    // 50048

  char* p = (char*)d_ws;
  auto alloc = [&](size_t bytes) -> char* {
    char* r = p;
    p += (bytes + 255) & ~(size_t)255;
    return r;
  };
  u16* A_bf  = (u16*)alloc((size_t)Mp * D_IN * 2);   // x bf16; later X2 (layer-2 A)
  u16* XLR1  = (u16*)alloc((size_t)Mp * 2048 * 2);   // [xl|xr] layer 1; later XLR2
  u16* W1t   = (u16*)alloc((size_t)2048 * D_IN * 2);
  u16* W2t   = (u16*)alloc((size_t)512 * C1 * 2);
  float* bc1 = (float*)alloc(2048 * 4);
  float* bc2 = (float*)alloc(512 * 4);
  int* counts = (int*)alloc((size_t)N * 4);
  int* cursor = (int*)alloc((size_t)N * 4);
  int* indptr = (int*)alloc((size_t)(N + 1) * 4);
  int* esrc   = (int*)alloc((size_t)E * 4);
  u16* X2   = A_bf;   // alias: A_bf dead after GEMM1
  u16* XLR2 = XLR1;   // alias: XLR1 dead after fused_edge1

  size_t need = (size_t)(p - (char*)d_ws);
  if (ws_size < need) {
    hipMemsetAsync(d_out, 0xFF, 4, stream);  // NaN sentinel
    return;
  }

  hipMemsetAsync(counts, 0, (size_t)N * 4, stream);
  hipMemsetAsync(cursor, 0, (size_t)N * 4, stream);

  // ---- casts / transposes / bias concat ----
  {
    long long tot = (long long)Mp * (D_IN / 8);
    cast_x_k<<<(int)((tot + 255) / 256), 256, 0, stream>>>(x, A_bf, N, Mp);
  }
  dim3 tb(32, 8);
  transpose_cast_k<<<dim3(D_IN / 32, C1 / 32), tb, 0, stream>>>(W1l, W1t, D_IN, C1);
  transpose_cast_k<<<dim3(D_IN / 32, C1 / 32), tb, 0, stream>>>(W1r, W1t + (size_t)1024 * D_IN, D_IN, C1);
  transpose_cast_k<<<dim3(C1 / 32, C2 / 32), tb, 0, stream>>>(W2l, W2t, C1, C2);
  transpose_cast_k<<<dim3(C1 / 32, C2 / 32), tb, 0, stream>>>(W2r, W2t + (size_t)256 * C1, C1, C2);
  concat_bias_k<<<8, 256, 0, stream>>>(b1l, b1r, bc1, 1024, 1024);
  concat_bias_k<<<2, 256, 0, stream>>>(b2l, b2r, bc2, 256, 256);

  // ---- CSR by dst (shared by both layers) ----
  count_k<<<1024, 256, 0, stream>>>(ei, counts, E0, E);
  scan_k<<<1, 256, 0, stream>>>(counts, indptr, N);
  scatter_k<<<1024, 256, 0, stream>>>(ei, indptr, cursor, esrc, E0, E);

  // ---- layer 1 ----
  gemm_bt_k<2048><<<dim3(Mp / 128, 2048 / 128), 256, 0, stream>>>(A_bf, W1t, bc1, XLR1, D_IN);
  fused_edge1_k<<<Mp, 256, 0, stream>>>(XLR1, indptr, esrc, att1, bias1, X2, N);

  // ---- layer 2 ----
  gemm_bt_k<512><<<dim3(Mp / 128, 512 / 128), 256, 0, stream>>>(X2, W2t, bc2, XLR2, C1);
  fused_edge2_k<<<(N + 3) / 4, 256, 0, stream>>>(XLR2, indptr, esrc, att2, bias2,
                                                 (float*)d_out, N);
}

// Round 3
// 918.644 us; speedup vs baseline: 1.5344x; 1.0182x over previous
//
#include <hip/hip_runtime.h>
#include <stdint.h>

#define D_IN 1024
#define C1   1024   // H1*HID
#define C2   256    // H2*HID
#define NEG  0.2f

typedef unsigned int u32;
typedef uint16_t u16;
typedef __attribute__((ext_vector_type(8))) short bf16x8;
typedef __attribute__((ext_vector_type(4))) float f32x4;

__device__ __forceinline__ float bf2f(u32 lo16) { return __uint_as_float(lo16 << 16); }
__device__ __forceinline__ u16 f2bf(float f) {
  u32 u = __float_as_uint(f);
  u += 0x7fffu + ((u >> 16) & 1u);   // RNE
  return (u16)(u >> 16);
}

__device__ __forceinline__ void gload16(const u16* g, u16* l) {
  __builtin_amdgcn_global_load_lds(
      (const __attribute__((address_space(1))) unsigned int*)g,
      (__attribute__((address_space(3))) unsigned int*)l,
      16, 0, 0);
}

// ---------------- cast x (f32) -> padded bf16 A [Mp][1024], zero pad rows ----
__global__ void cast_x_k(const float* __restrict__ x, u16* __restrict__ A,
                         int nrows, int Mp) {
  long long idx = (long long)blockIdx.x * blockDim.x + threadIdx.x;
  long long total = (long long)Mp * (D_IN / 8);
  if (idx >= total) return;
  long long base = idx * 8;
  int row = (int)(base >> 10);  // D_IN==1024
  u32 o0 = 0, o1 = 0, o2 = 0, o3 = 0;
  if (row < nrows) {
    const float4* px = (const float4*)(x + base);
    float4 v0 = px[0], v1 = px[1];
    o0 = (u32)f2bf(v0.x) | ((u32)f2bf(v0.y) << 16);
    o1 = (u32)f2bf(v0.z) | ((u32)f2bf(v0.w) << 16);
    o2 = (u32)f2bf(v1.x) | ((u32)f2bf(v1.y) << 16);
    o3 = (u32)f2bf(v1.z) | ((u32)f2bf(v1.w) << 16);
  }
  *(uint4*)(A + base) = make_uint4(o0, o1, o2, o3);
}

// ---------------- transpose+cast W [K][Nc] f32 -> Wt [Nc][K] bf16 ------------
__global__ void transpose_cast_k(const float* __restrict__ W, u16* __restrict__ Wt,
                                 int K, int Nc) {
  __shared__ float sh[32][33];
  int k0 = blockIdx.x * 32, n0 = blockIdx.y * 32;
  int tx = threadIdx.x, ty = threadIdx.y;  // block (32,8)
#pragma unroll
  for (int i = 0; i < 32; i += 8)
    sh[ty + i][tx] = W[(long long)(k0 + ty + i) * Nc + (n0 + tx)];
  __syncthreads();
#pragma unroll
  for (int i = 0; i < 32; i += 8)
    Wt[(long long)(n0 + ty + i) * K + (k0 + tx)] = f2bf(sh[tx][ty + i]);
}

// ---------------- concat two bias vectors -----------------------------------
__global__ void concat_bias_k(const float* __restrict__ a, const float* __restrict__ b,
                              float* __restrict__ o, int na, int nb) {
  int i = blockIdx.x * 256 + threadIdx.x;
  if (i < na) o[i] = a[i];
  else if (i < na + nb) o[i] = b[i - na];
}

// ---------------- bf16 MFMA GEMM: C[M][TN] = A[M][K] * Bt[TN][K]^T + bias ----
// 128x128 tile, BK=32, 4 waves x (4x4 16x16x32 frags).
// LDS XOR-swizzle with (row>>1)&3 (bank-quad-correct: chunk = 4*(row&1) +
// kg^((row>>1)&3) spreads 16 rows 2-way over 8 quads = conflict-free).
// XCD swizzle: consecutive blocks on an XCD share the A m-panel and sweep n,
// so the 256KB A-panel + whole Bt stay L2-resident.
template <int TN>
__global__ __launch_bounds__(256) void gemm_bt_k(
    const u16* __restrict__ A, const u16* __restrict__ Bt,
    const float* __restrict__ bias, u16* __restrict__ C, int K) {
  __shared__ u16 As[128 * 32];
  __shared__ u16 Bs[128 * 32];
  const int nx = gridDim.x, ny = gridDim.y;  // nx = M-tiles, ny = N-tiles
  const int nwg = nx * ny;
  int id = blockIdx.y * nx + blockIdx.x;
  int q = nwg >> 3, r = nwg & 7;
  int xcd = id & 7, loc = id >> 3;
  int sid = (xcd < r ? xcd * (q + 1) : r * (q + 1) + (xcd - r) * q) + loc;
  const int m0 = (sid / ny) * 128;   // n varies fastest within an XCD
  const int n0 = (sid % ny) * 128;

  const int tid = threadIdx.x;
  const int lane = tid & 63;
  const int wave = tid >> 6;
  const int wr = wave >> 1, wc = wave & 1;

  f32x4 acc[4][4] = {};

  const int srow = tid >> 2;                       // 0..63
  const int kgp = tid & 3;                         // physical k-chunk
  const int scol = (kgp ^ ((srow >> 1) & 3)) * 8;  // pre-swizzled source col
  const u16* gA0 = A + (long long)(m0 + srow) * K + scol;
  const u16* gA1 = A + (long long)(m0 + 64 + srow) * K + scol;
  const u16* gB0 = Bt + (long long)(n0 + srow) * K + scol;
  const u16* gB1 = Bt + (long long)(n0 + 64 + srow) * K + scol;
  u16* lA = As + wave * 512;
  u16* lB = Bs + wave * 512;

  for (int k0 = 0; k0 < K; k0 += 32) {
    gload16(gA0 + k0, lA);
    gload16(gA1 + k0, lA + 2048);
    gload16(gB0 + k0, lB);
    gload16(gB1 + k0, lB + 2048);
    asm volatile("s_waitcnt vmcnt(0)" ::: "memory");
    __syncthreads();

    bf16x8 av[4], bv[4];
#pragma unroll
    for (int m = 0; m < 4; m++) {
      int row = wr * 64 + m * 16 + (lane & 15);
      int kg = (lane >> 4) ^ ((row >> 1) & 3);
      av[m] = *(const bf16x8*)(As + row * 32 + kg * 8);
    }
#pragma unroll
    for (int n = 0; n < 4; n++) {
      int row = wc * 64 + n * 16 + (lane & 15);
      int kg = (lane >> 4) ^ ((row >> 1) & 3);
      bv[n] = *(const bf16x8*)(Bs + row * 32 + kg * 8);
    }
#pragma unroll
    for (int m = 0; m < 4; m++)
#pragma unroll
      for (int n = 0; n < 4; n++)
        acc[m][n] = __builtin_amdgcn_mfma_f32_16x16x32_bf16(av[m], bv[n], acc[m][n], 0, 0, 0);
    __syncthreads();
  }

#pragma unroll
  for (int m = 0; m < 4; m++) {
    int r0 = m0 + wr * 64 + m * 16 + ((lane >> 4) << 2);
#pragma unroll
    for (int n = 0; n < 4; n++) {
      int c = n0 + wc * 64 + n * 16 + (lane & 15);
      float b = bias[c];
#pragma unroll
      for (int j = 0; j < 4; j++)
        C[(long long)(r0 + j) * TN + c] = f2bf(acc[m][n][j] + b);
    }
  }
}

// ---------------- CSR build (by dst) ----------------------------------------
__global__ void count_k(const int* __restrict__ ei, int* __restrict__ counts,
                        int E0, int E) {
  for (int e = blockIdx.x * blockDim.x + threadIdx.x; e < E;
       e += gridDim.x * blockDim.x) {
    int dst = (e < E0) ? ei[E0 + e] : e - E0;
    atomicAdd(&counts[dst], 1);
  }
}

__global__ void scan_k(const int* __restrict__ counts, int* __restrict__ indptr, int n) {
  __shared__ int sh[256];
  __shared__ int carry_s;
  if (threadIdx.x == 0) carry_s = 0;
  __syncthreads();
  for (int base = 0; base < n; base += 256) {
    int i = base + threadIdx.x;
    int v = (i < n) ? counts[i] : 0;
    sh[threadIdx.x] = v;
    __syncthreads();
    int sum = v;
    for (int off = 1; off < 256; off <<= 1) {
      int t = (threadIdx.x >= off) ? sh[threadIdx.x - off] : 0;
      __syncthreads();
      sum += t;
      sh[threadIdx.x] = sum;
      __syncthreads();
    }
    int carry = carry_s;
    if (i < n) indptr[i] = carry + sum - v;
    __syncthreads();
    if (threadIdx.x == 255) carry_s = carry + sh[255];
    __syncthreads();
  }
  if (threadIdx.x == 0) indptr[n] = carry_s;
}

// store SRC id (not edge id) in CSR order
__global__ void scatter_k(const int* __restrict__ ei, const int* __restrict__ indptr,
                          int* __restrict__ cursor, int* __restrict__ esrc,
                          int E0, int E) {
  for (int e = blockIdx.x * blockDim.x + threadIdx.x; e < E;
       e += gridDim.x * blockDim.x) {
    int dst, src;
    if (e < E0) { src = ei[e]; dst = ei[E0 + e]; } else { src = dst = e - E0; }
    int pos = atomicAdd(&cursor[dst], 1);
    esrc[indptr[dst] + pos] = src;
  }
}

// ---------------- fused edge layer 1 (H=4): alpha+softmax+agg, online --------
__global__ __launch_bounds__(256) void fused_edge1_k(
    const u16* __restrict__ XLR, const int* __restrict__ indptr,
    const int* __restrict__ esrc, const float* __restrict__ att,
    const float* __restrict__ bias, u16* __restrict__ X2, int N) {
  int d = blockIdx.x;
  int tid = threadIdx.x;
  int c0 = tid * 4;  // channel in [0,1024); head = tid>>6
  if (d >= N) {
    *(ushort4*)(X2 + (long long)d * C1 + c0) = make_ushort4(0, 0, 0, 0);
    return;
  }
  ushort4 xr4 = *(const ushort4*)(XLR + (long long)d * 2048 + 1024 + c0);
  float xr0 = bf2f(xr4.x), xr1 = bf2f(xr4.y), xr2 = bf2f(xr4.z), xr3 = bf2f(xr4.w);
  float4 at = *(const float4*)(att + c0);

  float m = -INFINITY, l = 0.f;
  float a0 = 0.f, a1 = 0.f, a2 = 0.f, a3 = 0.f;
  int p = indptr[d], pend = indptr[d + 1];
  int src = esrc[p];
  ushort4 xl4 = *(const ushort4*)(XLR + (long long)src * 2048 + c0);
  while (p < pend) {
    ushort4 cur = xl4;
    int pn = p + 1;
    if (pn < pend) {
      int sn = esrc[pn];
      xl4 = *(const ushort4*)(XLR + (long long)sn * 2048 + c0);
    }
    float x0 = bf2f(cur.x), x1 = bf2f(cur.y), x2 = bf2f(cur.z), x3 = bf2f(cur.w);
    float m0 = x0 + xr0, m1 = x1 + xr1, m2 = x2 + xr2, m3 = x3 + xr3;
    float e0 = m0 > 0.f ? m0 : NEG * m0;
    float e1 = m1 > 0.f ? m1 : NEG * m1;
    float e2 = m2 > 0.f ? m2 : NEG * m2;
    float e3 = m3 > 0.f ? m3 : NEG * m3;
    float s = at.x * e0 + at.y * e1 + at.z * e2 + at.w * e3;
#pragma unroll
    for (int off = 1; off < 64; off <<= 1) s += __shfl_xor(s, off);
    float mnew = fmaxf(m, s);
    float scale = __expf(m - mnew);  // first iter: exp(-inf)=0
    float w = __expf(s - mnew);
    l = l * scale + w;
    a0 = a0 * scale + w * x0;
    a1 = a1 * scale + w * x1;
    a2 = a2 * scale + w * x2;
    a3 = a3 * scale + w * x3;
    m = mnew;
    p = pn;
  }
  float inv = 1.f / (l + 1e-16f);
  float4 b = *(const float4*)(bias + c0);
  ushort4 o;
  o.x = f2bf(fmaxf(a0 * inv + b.x, 0.f));
  o.y = f2bf(fmaxf(a1 * inv + b.y, 0.f));
  o.z = f2bf(fmaxf(a2 * inv + b.z, 0.f));
  o.w = f2bf(fmaxf(a3 * inv + b.w, 0.f));
  *(ushort4*)(X2 + (long long)d * C1 + c0) = o;
}

// ---------------- fused edge layer 2 (H=1): one wave per dst, f32 out --------
__global__ __launch_bounds__(256) void fused_edge2_k(
    const u16* __restrict__ XLR, const int* __restrict__ indptr,
    const int* __restrict__ esrc, const float* __restrict__ att,
    const float* __restrict__ bias, float* __restrict__ out, int N) {
  int d = blockIdx.x * 4 + (threadIdx.x >> 6);
  if (d >= N) return;
  int lane = threadIdx.x & 63;
  int c0 = lane * 4;
  ushort4 xr4 = *(const ushort4*)(XLR + (long long)d * 512 + 256 + c0);
  float xr0 = bf2f(xr4.x), xr1 = bf2f(xr4.y), xr2 = bf2f(xr4.z), xr3 = bf2f(xr4.w);
  float4 at = *(const float4*)(att + c0);

  float m = -INFINITY, l = 0.f;
  float a0 = 0.f, a1 = 0.f, a2 = 0.f, a3 = 0.f;
  int p = indptr[d], pend = indptr[d + 1];
  int src = esrc[p];
  ushort4 xl4 = *(const ushort4*)(XLR + (long long)src * 512 + c0);
  while (p < pend) {
    ushort4 cur = xl4;
    int pn = p + 1;
    if (pn < pend) {
      int sn = esrc[pn];
      xl4 = *(const ushort4*)(XLR + (long long)sn * 512 + c0);
    }
    float x0 = bf2f(cur.x), x1 = bf2f(cur.y), x2 = bf2f(cur.z), x3 = bf2f(cur.w);
    float m0 = x0 + xr0, m1 = x1 + xr1, m2 = x2 + xr2, m3 = x3 + xr3;
    float e0 = m0 > 0.f ? m0 : NEG * m0;
    float e1 = m1 > 0.f ? m1 : NEG * m1;
    float e2 = m2 > 0.f ? m2 : NEG * m2;
    float e3 = m3 > 0.f ? m3 : NEG * m3;
    float s = at.x * e0 + at.y * e1 + at.z * e2 + at.w * e3;
#pragma unroll
    for (int off = 1; off < 64; off <<= 1) s += __shfl_xor(s, off);
    float mnew = fmaxf(m, s);
    float scale = __expf(m - mnew);
    float w = __expf(s - mnew);
    l = l * scale + w;
    a0 = a0 * scale + w * x0;
    a1 = a1 * scale + w * x1;
    a2 = a2 * scale + w * x2;
    a3 = a3 * scale + w * x3;
    m = mnew;
    p = pn;
  }
  float inv = 1.f / (l + 1e-16f);
  float4 b = *(const float4*)(bias + c0);
  float4 o;
  o.x = fmaxf(a0 * inv + b.x, 0.f);
  o.y = fmaxf(a1 * inv + b.y, 0.f);
  o.z = fmaxf(a2 * inv + b.z, 0.f);
  o.w = fmaxf(a3 * inv + b.w, 0.f);
  *(float4*)(out + (long long)d * C2 + c0) = o;
}

// =============================================================================
extern "C" void kernel_launch(void* const* d_in, const int* in_sizes, int n_in,
                              void* d_out, int out_size, void* d_ws, size_t ws_size,
                              hipStream_t stream) {
  const float* x     = (const float*)d_in[0];
  const int*   ei    = (const int*)d_in[1];
  const float* W1l   = (const float*)d_in[2];
  const float* b1l   = (const float*)d_in[3];
  const float* W1r   = (const float*)d_in[4];
  const float* b1r   = (const float*)d_in[5];
  const float* att1  = (const float*)d_in[6];
  const float* bias1 = (const float*)d_in[7];
  const float* W2l   = (const float*)d_in[8];
  const float* b2l   = (const float*)d_in[9];
  const float* W2r   = (const float*)d_in[10];
  const float* b2r   = (const float*)d_in[11];
  const float* att2  = (const float*)d_in[12];
  const float* bias2 = (const float*)d_in[13];

  const int N  = in_sizes[0] / D_IN;  // 50000
  const int E0 = in_sizes[1] / 2;     // 400000
  const int E  = E0 + N;              // with self-loops
  const int Mp = (N + 127) & ~127;    // 50048

  char* p = (char*)d_ws;
  auto alloc = [&](size_t bytes) -> char* {
    char* r = p;
    p += (bytes + 255) & ~(size_t)255;
    return r;
  };
  u16* A_bf  = (u16*)alloc((size_t)Mp * D_IN * 2);   // x bf16; later X2 (layer-2 A)
  u16* XLR1  = (u16*)alloc((size_t)Mp * 2048 * 2);   // [xl|xr] layer 1; later XLR2
  u16* W1t   = (u16*)alloc((size_t)2048 * D_IN * 2);
  u16* W2t   = (u16*)alloc((size_t)512 * C1 * 2);
  float* bc1 = (float*)alloc(2048 * 4);
  float* bc2 = (float*)alloc(512 * 4);
  int* counts = (int*)alloc((size_t)N * 4);
  int* cursor = (int*)alloc((size_t)N * 4);
  int* indptr = (int*)alloc((size_t)(N + 1) * 4);
  int* esrc   = (int*)alloc((size_t)E * 4);
  u16* X2   = A_bf;   // alias: A_bf dead after GEMM1
  u16* XLR2 = XLR1;   // alias: XLR1 dead after fused_edge1

  size_t need = (size_t)(p - (char*)d_ws);
  if (ws_size < need) {
    hipMemsetAsync(d_out, 0xFF, 4, stream);  // NaN sentinel
    return;
  }

  hipMemsetAsync(counts, 0, (size_t)N * 4, stream);
  hipMemsetAsync(cursor, 0, (size_t)N * 4, stream);

  // ---- casts / transposes / bias concat ----
  {
    long long tot = (long long)Mp * (D_IN / 8);
    cast_x_k<<<(int)((tot + 255) / 256), 256, 0, stream>>>(x, A_bf, N, Mp);
  }
  dim3 tb(32, 8);
  transpose_cast_k<<<dim3(D_IN / 32, C1 / 32), tb, 0, stream>>>(W1l, W1t, D_IN, C1);
  transpose_cast_k<<<dim3(D_IN / 32, C1 / 32), tb, 0, stream>>>(W1r, W1t + (size_t)1024 * D_IN, D_IN, C1);
  transpose_cast_k<<<dim3(C1 / 32, C2 / 32), tb, 0, stream>>>(W2l, W2t, C1, C2);
  transpose_cast_k<<<dim3(C1 / 32, C2 / 32), tb, 0, stream>>>(W2r, W2t + (size_t)256 * C1, C1, C2);
  concat_bias_k<<<8, 256, 0, stream>>>(b1l, b1r, bc1, 1024, 1024);
  concat_bias_k<<<2, 256, 0, stream>>>(b2l, b2r, bc2, 256, 256);

  // ---- CSR by dst (shared by both layers) ----
  count_k<<<1024, 256, 0, stream>>>(ei, counts, E0, E);
  scan_k<<<1, 256, 0, stream>>>(counts, indptr, N);
  scatter_k<<<1024, 256, 0, stream>>>(ei, indptr, cursor, esrc, E0, E);

  // ---- layer 1 ----
  gemm_bt_k<2048><<<dim3(Mp / 128, 2048 / 128), 256, 0, stream>>>(A_bf, W1t, bc1, XLR1, D_IN);
  fused_edge1_k<<<Mp, 256, 0, stream>>>(XLR1, indptr, esrc, att1, bias1, X2, N);

  // ---- layer 2 ----
  gemm_bt_k<512><<<dim3(Mp / 128, 512 / 128), 256, 0, stream>>>(X2, W2t, bc2, XLR2, C1);
  fused_edge2_k<<<(N + 3) / 4, 256, 0, stream>>>(XLR2, indptr, esrc, att2, bias2,
                                                 (float*)d_out, N);
}

// Round 4
// 703.418 us; speedup vs baseline: 2.0039x; 1.3060x over previous
//
#include <hip/hip_runtime.h>
#include <stdint.h>

#define D_IN 1024
#define C1   1024   // H1*HID
#define C2   256    // H2*HID
#define NEG  0.2f

typedef unsigned int u32;
typedef uint16_t u16;
typedef __attribute__((ext_vector_type(8))) short bf16x8;
typedef __attribute__((ext_vector_type(4))) float f32x4;

__device__ __forceinline__ float bf2f(u32 lo16) { return __uint_as_float(lo16 << 16); }
__device__ __forceinline__ u16 f2bf(float f) {
  u32 u = __float_as_uint(f);
  u += 0x7fffu + ((u >> 16) & 1u);   // RNE
  return (u16)(u >> 16);
}

__device__ __forceinline__ void gload16(const u16* g, u16* l) {
  __builtin_amdgcn_global_load_lds(
      (const __attribute__((address_space(1))) unsigned int*)g,
      (__attribute__((address_space(3))) unsigned int*)l,
      16, 0, 0);
}

// ---------------- cast x (f32) -> padded bf16 A [Mp][1024], zero pad rows ----
__global__ void cast_x_k(const float* __restrict__ x, u16* __restrict__ A,
                         int nrows, int Mp) {
  long long idx = (long long)blockIdx.x * blockDim.x + threadIdx.x;
  long long total = (long long)Mp * (D_IN / 8);
  if (idx >= total) return;
  long long base = idx * 8;
  int row = (int)(base >> 10);  // D_IN==1024
  u32 o0 = 0, o1 = 0, o2 = 0, o3 = 0;
  if (row < nrows) {
    const float4* px = (const float4*)(x + base);
    float4 v0 = px[0], v1 = px[1];
    o0 = (u32)f2bf(v0.x) | ((u32)f2bf(v0.y) << 16);
    o1 = (u32)f2bf(v0.z) | ((u32)f2bf(v0.w) << 16);
    o2 = (u32)f2bf(v1.x) | ((u32)f2bf(v1.y) << 16);
    o3 = (u32)f2bf(v1.z) | ((u32)f2bf(v1.w) << 16);
  }
  *(uint4*)(A + base) = make_uint4(o0, o1, o2, o3);
}

// ---------------- transpose+cast W [K][Nc] f32 -> Wt [Nc][K] bf16 ------------
__global__ void transpose_cast_k(const float* __restrict__ W, u16* __restrict__ Wt,
                                 int K, int Nc) {
  __shared__ float sh[32][33];
  int k0 = blockIdx.x * 32, n0 = blockIdx.y * 32;
  int tx = threadIdx.x, ty = threadIdx.y;  // block (32,8)
#pragma unroll
  for (int i = 0; i < 32; i += 8)
    sh[ty + i][tx] = W[(long long)(k0 + ty + i) * Nc + (n0 + tx)];
  __syncthreads();
#pragma unroll
  for (int i = 0; i < 32; i += 8)
    Wt[(long long)(n0 + ty + i) * K + (k0 + tx)] = f2bf(sh[tx][ty + i]);
}

// ---------------- concat two bias vectors -----------------------------------
__global__ void concat_bias_k(const float* __restrict__ a, const float* __restrict__ b,
                              float* __restrict__ o, int na, int nb) {
  int i = blockIdx.x * 256 + threadIdx.x;
  if (i < na) o[i] = a[i];
  else if (i < na + nb) o[i] = b[i - na];
}

// ============ 256x256 BK=64 8-wave phase-interleaved MFMA GEMM ===============
// C[M][TN] = A[M][K] * Bt[TN][K]^T + bias.  512 thr = 8 waves (2M x 4N),
// per-wave 128x64 output (acc[8][4] 16x16 frags).  LDS 128 KiB:
// [dbuf2][half2][128x64] for A and B.  Per K-tile: 4 quadrant phases, each
// {ds_read subtile | stage 1 half-tile -> s_barrier -> setprio1 -> 16 MFMA ->
// setprio0 -> barrier}; counted s_waitcnt vmcnt(2) ONCE per K-tile (tail: 0).
// Stagger (race-free): phases 1-3 of tile t stage A1,B0,B1 of t+1 (other buf);
// phase 4 stages A0 of t+2 into buf[cur] whose A-half0 reads ended at ph3.
template <int TN>
__global__ __launch_bounds__(512, 2) void gemm8_k(
    const u16* __restrict__ A, const u16* __restrict__ Bt,
    const float* __restrict__ bias, u16* __restrict__ C, int K) {
  __shared__ u16 As[2][2][8192];
  __shared__ u16 Bs[2][2][8192];
  const int nx = gridDim.x, ny = gridDim.y;
  const int nwg = nx * ny;
  int id = blockIdx.y * nx + blockIdx.x;
  int q = nwg >> 3, r = nwg & 7;
  int xcd = id & 7, loc = id >> 3;
  int sid = (xcd < r ? xcd * (q + 1) : r * (q + 1) + (xcd - r) * q) + loc;
  const int m0 = (sid / ny) * 256;   // n varies fastest within an XCD
  const int n0 = (sid % ny) * 256;

  const int tid = threadIdx.x;
  const int lane = tid & 63;
  const int wave = tid >> 6;
  const int wm = wave >> 2;          // 0..1  (A half)
  const int wn = wave & 3;           // 0..3
  const int bh = wn >> 1;            // B half this wave reads
  const int bql = (wn & 1) * 2048;   // B quarter offset within half (u16)

  const int srow = tid >> 2;         // staging row 0..127
  const int kq   = tid & 3;          // physical k-chunk
  const int ksw  = (kq ^ ((srow >> 1) & 3)) * 8;  // swizzled src col (u16)

  const int nt = K / 64;

  const u16* gA[2] = { A + (long long)(m0 + srow) * K + ksw,
                       A + (long long)(m0 + 128 + srow) * K + ksw };
  const u16* gB[2] = { Bt + (long long)(n0 + srow) * K + ksw,
                       Bt + (long long)(n0 + 128 + srow) * K + ksw };

  auto stageA = [&](int kt, int h) {
    int db = kt & 1;
    gload16(gA[h] + kt * 64,      &As[db][h][tid * 8]);
    gload16(gA[h] + kt * 64 + 32, &As[db][h][4096 + tid * 8]);
  };
  auto stageB = [&](int kt, int h) {
    int db = kt & 1;
    gload16(gB[h] + kt * 64,      &Bs[db][h][tid * 8]);
    gload16(gB[h] + kt * 64 + 32, &Bs[db][h][4096 + tid * 8]);
  };

  // fragment read base: frow*32 + physchunk*8 (u16), physchunk = lq ^ s(frow)
  const int rbase = (lane & 15) * 32 + (((lane >> 4) ^ ((lane >> 1) & 3)) << 3);

  f32x4 acc[8][4] = {};
  bf16x8 av[4][2], bv[4][2];

  // ---- prologue: tile0 fully + A0(tile1); counted wait ----
  stageA(0, 0); stageA(0, 1); stageB(0, 0); stageB(0, 1);
  if (nt > 1) {
    stageA(1, 0);
    asm volatile("s_waitcnt vmcnt(2)" ::: "memory");
  } else {
    asm volatile("s_waitcnt vmcnt(0)" ::: "memory");
  }
  __builtin_amdgcn_s_barrier();

  for (int t = 0; t < nt; ++t) {
    const int cur = t & 1;
    const u16* Al = &As[cur][wm][0];
    const u16* Bl = &Bs[cur][bh][0];

    // ---- phase 1: quadrant (m-frags 0..3, n-frags 0..1) ----
#pragma unroll
    for (int i = 0; i < 4; ++i) {
      av[i][0] = *(const bf16x8*)(Al + i * 512 + rbase);
      av[i][1] = *(const bf16x8*)(Al + 4096 + i * 512 + rbase);
    }
#pragma unroll
    for (int j = 0; j < 2; ++j) {
      bv[j][0] = *(const bf16x8*)(Bl + bql + j * 512 + rbase);
      bv[j][1] = *(const bf16x8*)(Bl + 4096 + bql + j * 512 + rbase);
    }
    if (t + 1 < nt) stageA(t + 1, 1);
    __builtin_amdgcn_s_barrier();
    __builtin_amdgcn_s_setprio(1);
#pragma unroll
    for (int i = 0; i < 4; ++i)
#pragma unroll
      for (int j = 0; j < 2; ++j) {
        acc[i][j] = __builtin_amdgcn_mfma_f32_16x16x32_bf16(av[i][0], bv[j][0], acc[i][j], 0, 0, 0);
        acc[i][j] = __builtin_amdgcn_mfma_f32_16x16x32_bf16(av[i][1], bv[j][1], acc[i][j], 0, 0, 0);
      }
    __builtin_amdgcn_s_setprio(0);
    __builtin_amdgcn_s_barrier();

    // ---- phase 2: (m-frags 0..3, n-frags 2..3) ----
#pragma unroll
    for (int j = 2; j < 4; ++j) {
      bv[j][0] = *(const bf16x8*)(Bl + bql + j * 512 + rbase);
      bv[j][1] = *(const bf16x8*)(Bl + 4096 + bql + j * 512 + rbase);
    }
    if (t + 1 < nt) stageB(t + 1, 0);
    __builtin_amdgcn_s_barrier();
    __builtin_amdgcn_s_setprio(1);
#pragma unroll
    for (int i = 0; i < 4; ++i)
#pragma unroll
      for (int j = 2; j < 4; ++j) {
        acc[i][j] = __builtin_amdgcn_mfma_f32_16x16x32_bf16(av[i][0], bv[j][0], acc[i][j], 0, 0, 0);
        acc[i][j] = __builtin_amdgcn_mfma_f32_16x16x32_bf16(av[i][1], bv[j][1], acc[i][j], 0, 0, 0);
      }
    __builtin_amdgcn_s_setprio(0);
    __builtin_amdgcn_s_barrier();

    // ---- phase 3: (m-frags 4..7, n-frags 2..3) ----
#pragma unroll
    for (int i = 0; i < 4; ++i) {
      av[i][0] = *(const bf16x8*)(Al + (4 + i) * 512 + rbase);
      av[i][1] = *(const bf16x8*)(Al + 4096 + (4 + i) * 512 + rbase);
    }
    if (t + 1 < nt) stageB(t + 1, 1);
    __builtin_amdgcn_s_barrier();
    __builtin_amdgcn_s_setprio(1);
#pragma unroll
    for (int i = 0; i < 4; ++i)
#pragma unroll
      for (int j = 2; j < 4; ++j) {
        acc[4 + i][j] = __builtin_amdgcn_mfma_f32_16x16x32_bf16(av[i][0], bv[j][0], acc[4 + i][j], 0, 0, 0);
        acc[4 + i][j] = __builtin_amdgcn_mfma_f32_16x16x32_bf16(av[i][1], bv[j][1], acc[4 + i][j], 0, 0, 0);
      }
    __builtin_amdgcn_s_setprio(0);
    __builtin_amdgcn_s_barrier();

    // ---- phase 4: (m-frags 4..7, n-frags 0..1), no new ds_read ----
    if (t + 2 < nt) stageA(t + 2, 0);
    __builtin_amdgcn_s_barrier();
    __builtin_amdgcn_s_setprio(1);
#pragma unroll
    for (int i = 0; i < 4; ++i)
#pragma unroll
      for (int j = 0; j < 2; ++j) {
        acc[4 + i][j] = __builtin_amdgcn_mfma_f32_16x16x32_bf16(av[i][0], bv[j][0], acc[4 + i][j], 0, 0, 0);
        acc[4 + i][j] = __builtin_amdgcn_mfma_f32_16x16x32_bf16(av[i][1], bv[j][1], acc[4 + i][j], 0, 0, 0);
      }
    __builtin_amdgcn_s_setprio(0);
    if (t + 2 < nt) {
      asm volatile("s_waitcnt vmcnt(2)" ::: "memory");
    } else if (t + 1 < nt) {
      asm volatile("s_waitcnt vmcnt(0)" ::: "memory");
    }
    __builtin_amdgcn_s_barrier();
  }

  // ---- epilogue: D mapping col=lane&15, row=(lane>>4)*4+j ----
#pragma unroll
  for (int mf = 0; mf < 8; ++mf) {
    int r0 = m0 + wm * 128 + mf * 16 + ((lane >> 4) << 2);
#pragma unroll
    for (int nf = 0; nf < 4; ++nf) {
      int c = n0 + wn * 64 + nf * 16 + (lane & 15);
      float b = bias[c];
#pragma unroll
      for (int j = 0; j < 4; ++j)
        C[(long long)(r0 + j) * TN + c] = f2bf(acc[mf][nf][j] + b);
    }
  }
}

// ---------------- CSR build (by dst) ----------------------------------------
__global__ void count_k(const int* __restrict__ ei, int* __restrict__ counts,
                        int E0, int E) {
  for (int e = blockIdx.x * blockDim.x + threadIdx.x; e < E;
       e += gridDim.x * blockDim.x) {
    int dst = (e < E0) ? ei[E0 + e] : e - E0;
    atomicAdd(&counts[dst], 1);
  }
}

// hierarchical scan: blocksum -> scan partials (1 block) -> local scan + off
__global__ void blocksum_k(const int* __restrict__ counts, int* __restrict__ bsum, int n) {
  int i = blockIdx.x * 256 + threadIdx.x;
  int v = (i < n) ? counts[i] : 0;
#pragma unroll
  for (int off = 1; off < 64; off <<= 1) v += __shfl_xor(v, off);
  __shared__ int sh[4];
  if ((threadIdx.x & 63) == 0) sh[threadIdx.x >> 6] = v;
  __syncthreads();
  if (threadIdx.x == 0) bsum[blockIdx.x] = sh[0] + sh[1] + sh[2] + sh[3];
}

__global__ void scanb_k(const int* __restrict__ bsum, int* __restrict__ boff,
                        int nb, int* __restrict__ indptr, int n, int E) {
  __shared__ int sh[256];
  int i = threadIdx.x;
  int v = (i < nb) ? bsum[i] : 0;
  sh[i] = v;
  __syncthreads();
  int sum = v;
  for (int off = 1; off < 256; off <<= 1) {
    int t = (i >= off) ? sh[i - off] : 0;
    __syncthreads();
    sum += t;
    sh[i] = sum;
    __syncthreads();
  }
  if (i < nb) boff[i] = sum - v;  // exclusive
  if (i == 0) indptr[n] = E;
}

__global__ void scanf_k(const int* __restrict__ counts, const int* __restrict__ boff,
                        int* __restrict__ indptr, int n) {
  __shared__ int sh[256];
  int b = blockIdx.x;
  int i = b * 256 + threadIdx.x;
  int v = (i < n) ? counts[i] : 0;
  sh[threadIdx.x] = v;
  __syncthreads();
  int sum = v;
  for (int off = 1; off < 256; off <<= 1) {
    int t = (threadIdx.x >= off) ? sh[threadIdx.x - off] : 0;
    __syncthreads();
    sum += t;
    sh[threadIdx.x] = sum;
    __syncthreads();
  }
  if (i < n) indptr[i] = boff[b] + sum - v;
}

// store SRC id (not edge id) in CSR order
__global__ void scatter_k(const int* __restrict__ ei, const int* __restrict__ indptr,
                          int* __restrict__ cursor, int* __restrict__ esrc,
                          int E0, int E) {
  for (int e = blockIdx.x * blockDim.x + threadIdx.x; e < E;
       e += gridDim.x * blockDim.x) {
    int dst, src;
    if (e < E0) { src = ei[e]; dst = ei[E0 + e]; } else { src = dst = e - E0; }
    int pos = atomicAdd(&cursor[dst], 1);
    esrc[indptr[dst] + pos] = src;
  }
}

// ---------------- fused edge layer 1 (H=4): alpha+softmax+agg, online --------
__global__ __launch_bounds__(256) void fused_edge1_k(
    const u16* __restrict__ XLR, const int* __restrict__ indptr,
    const int* __restrict__ esrc, const float* __restrict__ att,
    const float* __restrict__ bias, u16* __restrict__ X2, int N) {
  int d = blockIdx.x;
  int tid = threadIdx.x;
  int c0 = tid * 4;  // channel in [0,1024); head = tid>>6
  if (d >= N) {
    *(ushort4*)(X2 + (long long)d * C1 + c0) = make_ushort4(0, 0, 0, 0);
    return;
  }
  ushort4 xr4 = *(const ushort4*)(XLR + (long long)d * 2048 + 1024 + c0);
  float xr0 = bf2f(xr4.x), xr1 = bf2f(xr4.y), xr2 = bf2f(xr4.z), xr3 = bf2f(xr4.w);
  float4 at = *(const float4*)(att + c0);

  float m = -INFINITY, l = 0.f;
  float a0 = 0.f, a1 = 0.f, a2 = 0.f, a3 = 0.f;
  int p = indptr[d], pend = indptr[d + 1];
  int src = esrc[p];
  ushort4 xl4 = *(const ushort4*)(XLR + (long long)src * 2048 + c0);
  while (p < pend) {
    ushort4 cur = xl4;
    int pn = p + 1;
    if (pn < pend) {
      int sn = esrc[pn];
      xl4 = *(const ushort4*)(XLR + (long long)sn * 2048 + c0);
    }
    float x0 = bf2f(cur.x), x1 = bf2f(cur.y), x2 = bf2f(cur.z), x3 = bf2f(cur.w);
    float m0 = x0 + xr0, m1 = x1 + xr1, m2 = x2 + xr2, m3 = x3 + xr3;
    float e0 = m0 > 0.f ? m0 : NEG * m0;
    float e1 = m1 > 0.f ? m1 : NEG * m1;
    float e2 = m2 > 0.f ? m2 : NEG * m2;
    float e3 = m3 > 0.f ? m3 : NEG * m3;
    float s = at.x * e0 + at.y * e1 + at.z * e2 + at.w * e3;
#pragma unroll
    for (int off = 1; off < 64; off <<= 1) s += __shfl_xor(s, off);
    float mnew = fmaxf(m, s);
    float scale = __expf(m - mnew);  // first iter: exp(-inf)=0
    float w = __expf(s - mnew);
    l = l * scale + w;
    a0 = a0 * scale + w * x0;
    a1 = a1 * scale + w * x1;
    a2 = a2 * scale + w * x2;
    a3 = a3 * scale + w * x3;
    m = mnew;
    p = pn;
  }
  float inv = 1.f / (l + 1e-16f);
  float4 b = *(const float4*)(bias + c0);
  ushort4 o;
  o.x = f2bf(fmaxf(a0 * inv + b.x, 0.f));
  o.y = f2bf(fmaxf(a1 * inv + b.y, 0.f));
  o.z = f2bf(fmaxf(a2 * inv + b.z, 0.f));
  o.w = f2bf(fmaxf(a3 * inv + b.w, 0.f));
  *(ushort4*)(X2 + (long long)d * C1 + c0) = o;
}

// ---------------- fused edge layer 2 (H=1): one wave per dst, f32 out --------
__global__ __launch_bounds__(256) void fused_edge2_k(
    const u16* __restrict__ XLR, const int* __restrict__ indptr,
    const int* __restrict__ esrc, const float* __restrict__ att,
    const float* __restrict__ bias, float* __restrict__ out, int N) {
  int d = blockIdx.x * 4 + (threadIdx.x >> 6);
  if (d >= N) return;
  int lane = threadIdx.x & 63;
  int c0 = lane * 4;
  ushort4 xr4 = *(const ushort4*)(XLR + (long long)d * 512 + 256 + c0);
  float xr0 = bf2f(xr4.x), xr1 = bf2f(xr4.y), xr2 = bf2f(xr4.z), xr3 = bf2f(xr4.w);
  float4 at = *(const float4*)(att + c0);

  float m = -INFINITY, l = 0.f;
  float a0 = 0.f, a1 = 0.f, a2 = 0.f, a3 = 0.f;
  int p = indptr[d], pend = indptr[d + 1];
  int src = esrc[p];
  ushort4 xl4 = *(const ushort4*)(XLR + (long long)src * 512 + c0);
  while (p < pend) {
    ushort4 cur = xl4;
    int pn = p + 1;
    if (pn < pend) {
      int sn = esrc[pn];
      xl4 = *(const ushort4*)(XLR + (long long)sn * 512 + c0);
    }
    float x0 = bf2f(cur.x), x1 = bf2f(cur.y), x2 = bf2f(cur.z), x3 = bf2f(cur.w);
    float m0 = x0 + xr0, m1 = x1 + xr1, m2 = x2 + xr2, m3 = x3 + xr3;
    float e0 = m0 > 0.f ? m0 : NEG * m0;
    float e1 = m1 > 0.f ? m1 : NEG * m1;
    float e2 = m2 > 0.f ? m2 : NEG * m2;
    float e3 = m3 > 0.f ? m3 : NEG * m3;
    float s = at.x * e0 + at.y * e1 + at.z * e2 + at.w * e3;
#pragma unroll
    for (int off = 1; off < 64; off <<= 1) s += __shfl_xor(s, off);
    float mnew = fmaxf(m, s);
    float scale = __expf(m - mnew);
    float w = __expf(s - mnew);
    l = l * scale + w;
    a0 = a0 * scale + w * x0;
    a1 = a1 * scale + w * x1;
    a2 = a2 * scale + w * x2;
    a3 = a3 * scale + w * x3;
    m = mnew;
    p = pn;
  }
  float inv = 1.f / (l + 1e-16f);
  float4 b = *(const float4*)(bias + c0);
  float4 o;
  o.x = fmaxf(a0 * inv + b.x, 0.f);
  o.y = fmaxf(a1 * inv + b.y, 0.f);
  o.z = fmaxf(a2 * inv + b.z, 0.f);
  o.w = fmaxf(a3 * inv + b.w, 0.f);
  *(float4*)(out + (long long)d * C2 + c0) = o;
}

// =============================================================================
extern "C" void kernel_launch(void* const* d_in, const int* in_sizes, int n_in,
                              void* d_out, int out_size, void* d_ws, size_t ws_size,
                              hipStream_t stream) {
  const float* x     = (const float*)d_in[0];
  const int*   ei    = (const int*)d_in[1];
  const float* W1l   = (const float*)d_in[2];
  const float* b1l   = (const float*)d_in[3];
  const float* W1r   = (const float*)d_in[4];
  const float* b1r   = (const float*)d_in[5];
  const float* att1  = (const float*)d_in[6];
  const float* bias1 = (const float*)d_in[7];
  const float* W2l   = (const float*)d_in[8];
  const float* b2l   = (const float*)d_in[9];
  const float* W2r   = (const float*)d_in[10];
  const float* b2r   = (const float*)d_in[11];
  const float* att2  = (const float*)d_in[12];
  const float* bias2 = (const float*)d_in[13];

  const int N  = in_sizes[0] / D_IN;  // 50000
  const int E0 = in_sizes[1] / 2;     // 400000
  const int E  = E0 + N;              // with self-loops
  const int Mp = (N + 255) & ~255;    // 50176 (multiple of 256)
  const int NB = (N + 255) / 256;     // scan blocks (196)

  char* p = (char*)d_ws;
  auto alloc = [&](size_t bytes) -> char* {
    char* r = p;
    p += (bytes + 255) & ~(size_t)255;
    return r;
  };
  u16* A_bf  = (u16*)alloc((size_t)Mp * D_IN * 2);   // x bf16; later X2 (layer-2 A)
  u16* XLR1  = (u16*)alloc((size_t)Mp * 2048 * 2);   // [xl|xr] layer 1; later XLR2
  u16* W1t   = (u16*)alloc((size_t)2048 * D_IN * 2);
  u16* W2t   = (u16*)alloc((size_t)512 * C1 * 2);
  float* bc1 = (float*)alloc(2048 * 4);
  float* bc2 = (float*)alloc(512 * 4);
  int* counts = (int*)alloc((size_t)N * 4);
  int* cursor = (int*)alloc((size_t)N * 4);
  int* indptr = (int*)alloc((size_t)(N + 1) * 4);
  int* esrc   = (int*)alloc((size_t)E * 4);
  int* bsum   = (int*)alloc((size_t)NB * 4);
  int* boff   = (int*)alloc((size_t)NB * 4);
  u16* X2   = A_bf;   // alias: A_bf dead after GEMM1
  u16* XLR2 = XLR1;   // alias: XLR1 dead after fused_edge1

  size_t need = (size_t)(p - (char*)d_ws);
  if (ws_size < need) {
    hipMemsetAsync(d_out, 0xFF, 4, stream);  // NaN sentinel
    return;
  }

  hipMemsetAsync(counts, 0, (size_t)N * 4, stream);
  hipMemsetAsync(cursor, 0, (size_t)N * 4, stream);

  // ---- casts / transposes / bias concat ----
  {
    long long tot = (long long)Mp * (D_IN / 8);
    cast_x_k<<<(int)((tot + 255) / 256), 256, 0, stream>>>(x, A_bf, N, Mp);
  }
  dim3 tb(32, 8);
  transpose_cast_k<<<dim3(D_IN / 32, C1 / 32), tb, 0, stream>>>(W1l, W1t, D_IN, C1);
  transpose_cast_k<<<dim3(D_IN / 32, C1 / 32), tb, 0, stream>>>(W1r, W1t + (size_t)1024 * D_IN, D_IN, C1);
  transpose_cast_k<<<dim3(C1 / 32, C2 / 32), tb, 0, stream>>>(W2l, W2t, C1, C2);
  transpose_cast_k<<<dim3(C1 / 32, C2 / 32), tb, 0, stream>>>(W2r, W2t + (size_t)256 * C1, C1, C2);
  concat_bias_k<<<8, 256, 0, stream>>>(b1l, b1r, bc1, 1024, 1024);
  concat_bias_k<<<2, 256, 0, stream>>>(b2l, b2r, bc2, 256, 256);

  // ---- CSR by dst (shared by both layers) ----
  count_k<<<1024, 256, 0, stream>>>(ei, counts, E0, E);
  blocksum_k<<<NB, 256, 0, stream>>>(counts, bsum, N);
  scanb_k<<<1, 256, 0, stream>>>(bsum, boff, NB, indptr, N, E);
  scanf_k<<<NB, 256, 0, stream>>>(counts, boff, indptr, N);
  scatter_k<<<1024, 256, 0, stream>>>(ei, indptr, cursor, esrc, E0, E);

  // ---- layer 1 ----
  gemm8_k<2048><<<dim3(Mp / 256, 2048 / 256), 512, 0, stream>>>(A_bf, W1t, bc1, XLR1, D_IN);
  fused_edge1_k<<<Mp, 256, 0, stream>>>(XLR1, indptr, esrc, att1, bias1, X2, N);

  // ---- layer 2 ----
  gemm8_k<512><<<dim3(Mp / 256, 512 / 256), 512, 0, stream>>>(X2, W2t, bc2, XLR2, C1);
  fused_edge2_k<<<(N + 3) / 4, 256, 0, stream>>>(XLR2, indptr, esrc, att2, bias2,
                                                 (float*)d_out, N);
}